// Round 1
// baseline (1147.910 us; speedup 1.0000x reference)
//
#include <hip/hip_runtime.h>
#include <math.h>

// Problem constants (T=1024, B=4, E=1024, H=16, D=64)
#define TQ 1024
#define BBATCH 4
#define EDIM 1024
#define HHEADS 16
#define DHEAD 64

// ---------------------------------------------------------------------------
// GEMM: C = A * B^T + bias.  A: MxK row-major, B: NxK row-major.
// MODE 0: C[m][n] linear MxN.  MODE 1: scatter to R[h][t][d] (h=n>>6, t=m, d=n&63).
// Tile 128x128, BK=16, 256 threads, 8x8 per thread (2x2 blocks of 4x4).
// ---------------------------------------------------------------------------
template<int MODE>
__global__ __launch_bounds__(256) void gemm_abt(
    const float* __restrict__ A, const float* __restrict__ B,
    const float* __restrict__ bias, float* __restrict__ C,
    int M, int N, int K)
{
    __shared__ __align__(16) float As[16][132];
    __shared__ __align__(16) float Bs[16][132];
    const int tid = threadIdx.x;
    const int tx = tid & 15, ty = tid >> 4;
    const int m0 = blockIdx.y * 128, n0 = blockIdx.x * 128;

    float acc[2][2][4][4] = {};

    for (int k0 = 0; k0 < K; k0 += 16) {
        #pragma unroll
        for (int s = 0; s < 2; ++s) {
            int idx = s * 256 + tid;          // 0..511
            int m  = idx >> 2;                // 0..127
            int kc = (idx & 3) << 2;          // 0,4,8,12
            const float4 va = *(const float4*)&A[(size_t)(m0 + m) * K + k0 + kc];
            As[kc + 0][m] = va.x; As[kc + 1][m] = va.y;
            As[kc + 2][m] = va.z; As[kc + 3][m] = va.w;
            const float4 vb = *(const float4*)&B[(size_t)(n0 + m) * K + k0 + kc];
            Bs[kc + 0][m] = vb.x; Bs[kc + 1][m] = vb.y;
            Bs[kc + 2][m] = vb.z; Bs[kc + 3][m] = vb.w;
        }
        __syncthreads();
        #pragma unroll
        for (int kk = 0; kk < 16; ++kk) {
            float4 a0 = *(const float4*)&As[kk][ty * 4];
            float4 a1 = *(const float4*)&As[kk][64 + ty * 4];
            float4 b0 = *(const float4*)&Bs[kk][tx * 4];
            float4 b1 = *(const float4*)&Bs[kk][64 + tx * 4];
            float av[2][4] = {{a0.x, a0.y, a0.z, a0.w}, {a1.x, a1.y, a1.z, a1.w}};
            float bv[2][4] = {{b0.x, b0.y, b0.z, b0.w}, {b1.x, b1.y, b1.z, b1.w}};
            #pragma unroll
            for (int si = 0; si < 2; ++si)
            #pragma unroll
            for (int sj = 0; sj < 2; ++sj)
            #pragma unroll
            for (int i = 0; i < 4; ++i)
            #pragma unroll
            for (int j = 0; j < 4; ++j)
                acc[si][sj][i][j] += av[si][i] * bv[sj][j];
        }
        __syncthreads();
    }

    #pragma unroll
    for (int si = 0; si < 2; ++si)
    #pragma unroll
    for (int sj = 0; sj < 2; ++sj)
    #pragma unroll
    for (int i = 0; i < 4; ++i) {
        int m = m0 + si * 64 + ty * 4 + i;
        int n = n0 + sj * 64 + tx * 4;
        float4 v;
        v.x = acc[si][sj][i][0] + bias[n + 0];
        v.y = acc[si][sj][i][1] + bias[n + 1];
        v.z = acc[si][sj][i][2] + bias[n + 2];
        v.w = acc[si][sj][i][3] + bias[n + 3];
        if (MODE == 0) {
            *(float4*)&C[(size_t)m * N + n] = v;
        } else {
            // R[h][t][d]
            *(float4*)&C[(((size_t)(n >> 6) << 10) + m) * 64 + (n & 63)] = v;
        }
    }
}

// ---------------------------------------------------------------------------
// Score kernel: for one (b,h) and one 64x64 (q,k) tile with k0 <= q0:
//   S[q][k] = 0.125 * [ (Q[q]+rwb)·K[k] + (Q[q]+rrb)·R[k-q+1023] ]
// Written straight into the attn region of d_out (softmax runs in-place later).
// Tiles fully above the diagonal are skipped (masked anyway).
// ---------------------------------------------------------------------------
__global__ __launch_bounds__(256) void score_kernel(
    const float* __restrict__ qkv, const float* __restrict__ R,
    const float* __restrict__ rwb, const float* __restrict__ rrb,
    float* __restrict__ attn)
{
    const int kt = blockIdx.x, qt = blockIdx.y;
    if (kt > qt) return;
    const int bh = blockIdx.z;
    const int b = bh >> 4, h = bh & 15;
    const int q0 = qt << 6, k0 = kt << 6;
    const int tid = threadIdx.x;
    const int tx = tid & 15, ty = tid >> 4;

    __shared__ __align__(16) float Qs[64][68];    // [q][d]
    __shared__ __align__(16) float Kst[64][68];   // [d][k]  (transposed)
    __shared__ __align__(16) float Rst[64][129];  // [d][jwin] (transposed, 127 used)
    __shared__ float rwb_s[64], rrb_s[64];

    if (tid < 64) {
        rwb_s[tid] = rwb[(h << 6) + tid];
        rrb_s[tid] = rrb[(h << 6) + tid];
    }

    // load Q tile (straight) and K tile (transposed)
    #pragma unroll
    for (int s = 0; s < 4; ++s) {
        int idx = s * 256 + tid;           // 0..1023
        int r = idx >> 4;                  // 0..63
        int dc = (idx & 15) << 2;          // 0..60
        float4 vq = *(const float4*)&qkv[((size_t)(q0 + r) * 4 + b) * 3072 + h * 192 + dc];
        *(float4*)&Qs[r][dc] = vq;
        float4 vk = *(const float4*)&qkv[((size_t)(k0 + r) * 4 + b) * 3072 + h * 192 + 64 + dc];
        Kst[dc + 0][r] = vk.x; Kst[dc + 1][r] = vk.y;
        Kst[dc + 2][r] = vk.z; Kst[dc + 3][r] = vk.w;
    }
    // load R window rows j = base_j + jr, jr in [0,127)  (clamped; clamped rows
    // only feed masked entries)
    const int base_j = k0 - q0 + 960;      // >= 0 since k0 <= q0
    #pragma unroll
    for (int s = 0; s < 8; ++s) {
        int idx = s * 256 + tid;
        if (idx < 2032) {                  // 127*16
            int jr = idx >> 4;
            int dc = (idx & 15) << 2;
            int j = base_j + jr; if (j > 1023) j = 1023;
            float4 v = *(const float4*)&R[(((size_t)h << 10) + j) * 64 + dc];
            Rst[dc + 0][jr] = v.x; Rst[dc + 1][jr] = v.y;
            Rst[dc + 2][jr] = v.z; Rst[dc + 3][jr] = v.w;
        }
    }
    __syncthreads();

    float acc[4][4] = {};
    const int rb = ((tx - ty) << 2) + 60;  // window base for (i=j): in [0,120]
    #pragma unroll 4
    for (int d = 0; d < 64; ++d) {
        float rwd = rwb_s[d], rrd = rrb_s[d];
        float t1[4], t2[4];
        #pragma unroll
        for (int i = 0; i < 4; ++i) {
            float aq = Qs[(ty << 2) + i][d];
            t1[i] = aq + rwd;
            t2[i] = aq + rrd;
        }
        float4 kv = *(const float4*)&Kst[d][tx << 2];
        float kvv[4] = {kv.x, kv.y, kv.z, kv.w};
        float rv[7];
        #pragma unroll
        for (int o = 0; o < 7; ++o) rv[o] = Rst[d][rb + o];
        #pragma unroll
        for (int i = 0; i < 4; ++i)
        #pragma unroll
        for (int j = 0; j < 4; ++j)
            acc[i][j] += t1[i] * kvv[j] + t2[i] * rv[j - i + 3];
    }

    #pragma unroll
    for (int i = 0; i < 4; ++i) {
        int q = q0 + (ty << 2) + i;
        float4 v;
        v.x = acc[i][0] * 0.125f; v.y = acc[i][1] * 0.125f;
        v.z = acc[i][2] * 0.125f; v.w = acc[i][3] * 0.125f;
        *(float4*)&attn[((((size_t)bh << 10) + q) << 10) + k0 + (tx << 2)] = v;
    }
}

// ---------------------------------------------------------------------------
// In-place causal softmax over each attn row. Writes exact 0 for k > q.
// One block (256 thr) per (bh, q) row of 1024.
// ---------------------------------------------------------------------------
__global__ __launch_bounds__(256) void softmax_kernel(float* __restrict__ attn)
{
    const int q = blockIdx.x, bh = blockIdx.y;
    float* row = attn + ((((size_t)bh << 10) + q) << 10);
    const int tid = threadIdx.x;
    float4 v = *(const float4*)&row[tid << 2];
    float s[4] = {v.x, v.y, v.z, v.w};
    #pragma unroll
    for (int c = 0; c < 4; ++c)
        if (((tid << 2) + c) > q) s[c] = -INFINITY;

    float m = fmaxf(fmaxf(s[0], s[1]), fmaxf(s[2], s[3]));
    #pragma unroll
    for (int off = 32; off > 0; off >>= 1)
        m = fmaxf(m, __shfl_xor(m, off));
    __shared__ float redm[4];
    __shared__ float reds[4];
    const int lane = tid & 63, wid = tid >> 6;
    if (lane == 0) redm[wid] = m;
    __syncthreads();
    m = fmaxf(fmaxf(redm[0], redm[1]), fmaxf(redm[2], redm[3]));

    float e[4];
    float t = 0.f;
    #pragma unroll
    for (int c = 0; c < 4; ++c) { e[c] = expf(s[c] - m); t += e[c]; }
    #pragma unroll
    for (int off = 32; off > 0; off >>= 1)
        t += __shfl_xor(t, off);
    if (lane == 0) reds[wid] = t;
    __syncthreads();
    t = reds[0] + reds[1] + reds[2] + reds[3];
    float inv = 1.0f / t;
    float4 o;
    o.x = e[0] * inv; o.y = e[1] * inv; o.z = e[2] * inv; o.w = e[3] * inv;
    *(float4*)&row[tid << 2] = o;
}

// ---------------------------------------------------------------------------
// ctx[q][b][h*64+d] = sum_k attn[bh][q][k] * V[k]   (k-tiles 0..qt; attn is 0
// beyond the diagonal so in-tile masked entries contribute nothing)
// ---------------------------------------------------------------------------
__global__ __launch_bounds__(256) void ctx_kernel(
    const float* __restrict__ attn, const float* __restrict__ qkv,
    float* __restrict__ ctx)
{
    const int qt = blockIdx.x, bh = blockIdx.y;
    const int b = bh >> 4, h = bh & 15;
    const int q0 = qt << 6;
    const int tid = threadIdx.x, tx = tid & 15, ty = tid >> 4;
    __shared__ __align__(16) float At[64][68];  // [q][k]
    __shared__ __align__(16) float Vs[64][68];  // [k][d]
    float acc[4][4] = {};

    for (int k0 = 0; k0 <= q0; k0 += 64) {
        #pragma unroll
        for (int s = 0; s < 4; ++s) {
            int idx = s * 256 + tid;
            int r = idx >> 4, cc = (idx & 15) << 2;
            *(float4*)&At[r][cc] =
                *(const float4*)&attn[((((size_t)bh << 10) + q0 + r) << 10) + k0 + cc];
            *(float4*)&Vs[r][cc] =
                *(const float4*)&qkv[((size_t)(k0 + r) * 4 + b) * 3072 + h * 192 + 128 + cc];
        }
        __syncthreads();
        #pragma unroll
        for (int kk = 0; kk < 64; ++kk) {
            float a[4];
            #pragma unroll
            for (int i = 0; i < 4; ++i) a[i] = At[(ty << 2) + i][kk];
            float4 vv = *(const float4*)&Vs[kk][tx << 2];
            float vb[4] = {vv.x, vv.y, vv.z, vv.w};
            #pragma unroll
            for (int i = 0; i < 4; ++i)
            #pragma unroll
            for (int j = 0; j < 4; ++j)
                acc[i][j] += a[i] * vb[j];
        }
        __syncthreads();
    }

    #pragma unroll
    for (int i = 0; i < 4; ++i) {
        int q = q0 + (ty << 2) + i;
        float4 o;
        o.x = acc[i][0]; o.y = acc[i][1]; o.z = acc[i][2]; o.w = acc[i][3];
        *(float4*)&ctx[((size_t)q * 4 + b) * 1024 + (h << 6) + (tx << 2)] = o;
    }
}

// ---------------------------------------------------------------------------
extern "C" void kernel_launch(void* const* d_in, const int* in_sizes, int n_in,
                              void* d_out, int out_size, void* d_ws, size_t ws_size,
                              hipStream_t stream)
{
    (void)in_sizes; (void)n_in; (void)out_size; (void)ws_size;
    const float* x     = (const float*)d_in[0];
    const float* pos   = (const float*)d_in[1];
    const float* w_in  = (const float*)d_in[2];
    const float* b_in  = (const float*)d_in[3];
    const float* w_out = (const float*)d_in[4];
    const float* b_out = (const float*)d_in[5];
    const float* w_pos = (const float*)d_in[6];
    const float* b_pos = (const float*)d_in[7];
    const float* rwb   = (const float*)d_in[8];
    const float* rrb   = (const float*)d_in[9];
    // d_in[10] = attn_mask: causal triu(k=1) by construction — handled analytically.

    float* out  = (float*)d_out;                       // (T,B,E)    4,194,304
    float* attn = out + (size_t)TQ * BBATCH * EDIM;    // (B,H,T,T) 67,108,864

    float* ws  = (float*)d_ws;
    float* qkv = ws;                                   // 4096 x 3072
    float* R   = qkv + (size_t)4096 * 3072;            // [H][T][D]
    float* ctx = R + (size_t)HHEADS * TQ * DHEAD;      // (T,B,E)

    dim3 blk(256, 1, 1);

    // 1) qkv = x2d @ W_in^T + b_in        (4096 x 3072)
    gemm_abt<0><<<dim3(3072 / 128, 4096 / 128), blk, 0, stream>>>(
        x, w_in, b_in, qkv, 4096, 3072, 1024);
    // 2) r_head_k = pos @ W_pos^T + b_pos -> R[h][t][d]
    gemm_abt<1><<<dim3(1024 / 128, 1024 / 128), blk, 0, stream>>>(
        pos, w_pos, b_pos, R, 1024, 1024, 1024);
    // 3) scores -> attn region (lower-triangle tiles only)
    score_kernel<<<dim3(16, 16, 64), blk, 0, stream>>>(qkv, R, rwb, rrb, attn);
    // 4) in-place causal softmax (writes zeros above diagonal)
    softmax_kernel<<<dim3(1024, 64), blk, 0, stream>>>(attn);
    // 5) ctx = attn @ V
    ctx_kernel<<<dim3(16, 64), blk, 0, stream>>>(attn, qkv, ctx);
    // 6) out = ctx2d @ W_out^T + b_out
    gemm_abt<0><<<dim3(1024 / 128, 4096 / 128), blk, 0, stream>>>(
        ctx, w_out, b_out, out, 4096, 1024, 1024);
}

// Round 2
// 748.152 us; speedup vs baseline: 1.5343x; 1.5343x over previous
//
#include <hip/hip_runtime.h>
#include <math.h>

// Problem constants (T=1024, B=4, E=1024, H=16, D=64)
#define TQ 1024
#define BBATCH 4
#define EDIM 1024
#define HHEADS 16
#define DHEAD 64

typedef __bf16 bf16x8 __attribute__((ext_vector_type(8)));
typedef float  f32x4  __attribute__((ext_vector_type(4)));

#define LDK 40  // LDS row stride in bf16 elems: 32 + 8 pad => 80B rows, kills 8-way conflicts

// ---------------------------------------------------------------------------
// MFMA GEMM: C = A * B^T + bias (fp32 in/out, bf16 MFMA internally).
// A: MxK row-major fp32, B: NxK row-major fp32.
// MODE 0: C[m][n] linear MxN.  MODE 1: scatter to R[h][t][d] (h=n>>6, t=m, d=n&63).
// 128x128 tile, BK=32, 256 threads = 4 waves in 2x2, each wave owns 64x64 out.
// ---------------------------------------------------------------------------
template<int MODE>
__global__ __launch_bounds__(256) void gemm_mfma_abt(
    const float* __restrict__ A, const float* __restrict__ B,
    const float* __restrict__ bias, float* __restrict__ C,
    int M, int N, int K)
{
    __shared__ __bf16 As[128 * LDK];
    __shared__ __bf16 Bs[128 * LDK];
    const int tid  = threadIdx.x;
    const int lane = tid & 63;
    const int wid  = tid >> 6;
    const int wr   = wid >> 1, wc = wid & 1;
    const int m0 = blockIdx.y * 128, n0 = blockIdx.x * 128;

    f32x4 acc[4][4] = {};   // [mi][ni], 16 fragments of 16x16

    // staging slots: octet o in {tid, tid+256}: row = o>>2 (0..127), k = (o&3)*8
    const int sm0 = tid >> 2;        // rows 0..63
    const int sm1 = sm0 + 64;        // rows 64..127
    const int sk  = (tid & 3) << 3;  // 0,8,16,24

    const int fr = lane & 15;        // fragment row/col within 16
    const int kg = (lane >> 4) << 3; // k-octet base: 0,8,16,24

    for (int k0 = 0; k0 < K; k0 += 32) {
        // global loads (fp32) into regs — before barrier so latency overlaps MFMA drain
        float4 ra0a = *(const float4*)&A[(size_t)(m0 + sm0) * K + k0 + sk];
        float4 ra0b = *(const float4*)&A[(size_t)(m0 + sm0) * K + k0 + sk + 4];
        float4 ra1a = *(const float4*)&A[(size_t)(m0 + sm1) * K + k0 + sk];
        float4 ra1b = *(const float4*)&A[(size_t)(m0 + sm1) * K + k0 + sk + 4];
        float4 rb0a = *(const float4*)&B[(size_t)(n0 + sm0) * K + k0 + sk];
        float4 rb0b = *(const float4*)&B[(size_t)(n0 + sm0) * K + k0 + sk + 4];
        float4 rb1a = *(const float4*)&B[(size_t)(n0 + sm1) * K + k0 + sk];
        float4 rb1b = *(const float4*)&B[(size_t)(n0 + sm1) * K + k0 + sk + 4];

        __syncthreads();  // previous iteration's fragment reads complete

        bf16x8 w;
        w[0]=(__bf16)ra0a.x; w[1]=(__bf16)ra0a.y; w[2]=(__bf16)ra0a.z; w[3]=(__bf16)ra0a.w;
        w[4]=(__bf16)ra0b.x; w[5]=(__bf16)ra0b.y; w[6]=(__bf16)ra0b.z; w[7]=(__bf16)ra0b.w;
        *(bf16x8*)&As[sm0 * LDK + sk] = w;
        w[0]=(__bf16)ra1a.x; w[1]=(__bf16)ra1a.y; w[2]=(__bf16)ra1a.z; w[3]=(__bf16)ra1a.w;
        w[4]=(__bf16)ra1b.x; w[5]=(__bf16)ra1b.y; w[6]=(__bf16)ra1b.z; w[7]=(__bf16)ra1b.w;
        *(bf16x8*)&As[sm1 * LDK + sk] = w;
        w[0]=(__bf16)rb0a.x; w[1]=(__bf16)rb0a.y; w[2]=(__bf16)rb0a.z; w[3]=(__bf16)rb0a.w;
        w[4]=(__bf16)rb0b.x; w[5]=(__bf16)rb0b.y; w[6]=(__bf16)rb0b.z; w[7]=(__bf16)rb0b.w;
        *(bf16x8*)&Bs[sm0 * LDK + sk] = w;
        w[0]=(__bf16)rb1a.x; w[1]=(__bf16)rb1a.y; w[2]=(__bf16)rb1a.z; w[3]=(__bf16)rb1a.w;
        w[4]=(__bf16)rb1b.x; w[5]=(__bf16)rb1b.y; w[6]=(__bf16)rb1b.z; w[7]=(__bf16)rb1b.w;
        *(bf16x8*)&Bs[sm1 * LDK + sk] = w;

        __syncthreads();  // tiles visible

        bf16x8 af[4], bf[4];
        #pragma unroll
        for (int i = 0; i < 4; ++i) {
            af[i] = *(const bf16x8*)&As[(wr * 64 + i * 16 + fr) * LDK + kg];
            bf[i] = *(const bf16x8*)&Bs[(wc * 64 + i * 16 + fr) * LDK + kg];
        }
        #pragma unroll
        for (int mi = 0; mi < 4; ++mi)
        #pragma unroll
        for (int ni = 0; ni < 4; ++ni)
            acc[mi][ni] = __builtin_amdgcn_mfma_f32_16x16x32_bf16(
                af[mi], bf[ni], acc[mi][ni], 0, 0, 0);
    }

    // epilogue: C/D layout col=lane&15, row=(lane>>4)*4+reg   [m89-verified]
    const int fq = lane >> 4;
    #pragma unroll
    for (int mi = 0; mi < 4; ++mi)
    #pragma unroll
    for (int ni = 0; ni < 4; ++ni) {
        int row = m0 + wr * 64 + mi * 16 + fq * 4;
        int col = n0 + wc * 64 + ni * 16 + fr;
        float bv = bias[col];
        #pragma unroll
        for (int j = 0; j < 4; ++j) {
            float v = acc[mi][ni][j] + bv;
            if (MODE == 0) {
                C[(size_t)(row + j) * N + col] = v;
            } else {
                C[(((size_t)(col >> 6) << 10) + (row + j)) * 64 + (col & 63)] = v;
            }
        }
    }
}

// ---------------------------------------------------------------------------
// Score kernel (unchanged from round 1): for one (b,h) and one 64x64 (q,k)
// tile with k0 <= q0:
//   S[q][k] = 0.125 * [ (Q[q]+rwb)·K[k] + (Q[q]+rrb)·R[k-q+1023] ]
// ---------------------------------------------------------------------------
__global__ __launch_bounds__(256) void score_kernel(
    const float* __restrict__ qkv, const float* __restrict__ R,
    const float* __restrict__ rwb, const float* __restrict__ rrb,
    float* __restrict__ attn)
{
    const int kt = blockIdx.x, qt = blockIdx.y;
    if (kt > qt) return;
    const int bh = blockIdx.z;
    const int b = bh >> 4, h = bh & 15;
    const int q0 = qt << 6, k0 = kt << 6;
    const int tid = threadIdx.x;
    const int tx = tid & 15, ty = tid >> 4;

    __shared__ __align__(16) float Qs[64][68];
    __shared__ __align__(16) float Kst[64][68];
    __shared__ __align__(16) float Rst[64][129];
    __shared__ float rwb_s[64], rrb_s[64];

    if (tid < 64) {
        rwb_s[tid] = rwb[(h << 6) + tid];
        rrb_s[tid] = rrb[(h << 6) + tid];
    }

    #pragma unroll
    for (int s = 0; s < 4; ++s) {
        int idx = s * 256 + tid;
        int r = idx >> 4;
        int dc = (idx & 15) << 2;
        float4 vq = *(const float4*)&qkv[((size_t)(q0 + r) * 4 + b) * 3072 + h * 192 + dc];
        *(float4*)&Qs[r][dc] = vq;
        float4 vk = *(const float4*)&qkv[((size_t)(k0 + r) * 4 + b) * 3072 + h * 192 + 64 + dc];
        Kst[dc + 0][r] = vk.x; Kst[dc + 1][r] = vk.y;
        Kst[dc + 2][r] = vk.z; Kst[dc + 3][r] = vk.w;
    }
    const int base_j = k0 - q0 + 960;
    #pragma unroll
    for (int s = 0; s < 8; ++s) {
        int idx = s * 256 + tid;
        if (idx < 2032) {
            int jr = idx >> 4;
            int dc = (idx & 15) << 2;
            int j = base_j + jr; if (j > 1023) j = 1023;
            float4 v = *(const float4*)&R[(((size_t)h << 10) + j) * 64 + dc];
            Rst[dc + 0][jr] = v.x; Rst[dc + 1][jr] = v.y;
            Rst[dc + 2][jr] = v.z; Rst[dc + 3][jr] = v.w;
        }
    }
    __syncthreads();

    float acc[4][4] = {};
    const int rb = ((tx - ty) << 2) + 60;
    #pragma unroll 4
    for (int d = 0; d < 64; ++d) {
        float rwd = rwb_s[d], rrd = rrb_s[d];
        float t1[4], t2[4];
        #pragma unroll
        for (int i = 0; i < 4; ++i) {
            float aq = Qs[(ty << 2) + i][d];
            t1[i] = aq + rwd;
            t2[i] = aq + rrd;
        }
        float4 kv = *(const float4*)&Kst[d][tx << 2];
        float kvv[4] = {kv.x, kv.y, kv.z, kv.w};
        float rv[7];
        #pragma unroll
        for (int o = 0; o < 7; ++o) rv[o] = Rst[d][rb + o];
        #pragma unroll
        for (int i = 0; i < 4; ++i)
        #pragma unroll
        for (int j = 0; j < 4; ++j)
            acc[i][j] += t1[i] * kvv[j] + t2[i] * rv[j - i + 3];
    }

    #pragma unroll
    for (int i = 0; i < 4; ++i) {
        int q = q0 + (ty << 2) + i;
        float4 v;
        v.x = acc[i][0] * 0.125f; v.y = acc[i][1] * 0.125f;
        v.z = acc[i][2] * 0.125f; v.w = acc[i][3] * 0.125f;
        *(float4*)&attn[((((size_t)bh << 10) + q) << 10) + k0 + (tx << 2)] = v;
    }
}

// ---------------------------------------------------------------------------
// In-place causal softmax (unchanged).
// ---------------------------------------------------------------------------
__global__ __launch_bounds__(256) void softmax_kernel(float* __restrict__ attn)
{
    const int q = blockIdx.x, bh = blockIdx.y;
    float* row = attn + ((((size_t)bh << 10) + q) << 10);
    const int tid = threadIdx.x;
    float4 v = *(const float4*)&row[tid << 2];
    float s[4] = {v.x, v.y, v.z, v.w};
    #pragma unroll
    for (int c = 0; c < 4; ++c)
        if (((tid << 2) + c) > q) s[c] = -INFINITY;

    float m = fmaxf(fmaxf(s[0], s[1]), fmaxf(s[2], s[3]));
    #pragma unroll
    for (int off = 32; off > 0; off >>= 1)
        m = fmaxf(m, __shfl_xor(m, off));
    __shared__ float redm[4];
    __shared__ float reds[4];
    const int lane = tid & 63, wid = tid >> 6;
    if (lane == 0) redm[wid] = m;
    __syncthreads();
    m = fmaxf(fmaxf(redm[0], redm[1]), fmaxf(redm[2], redm[3]));

    float e[4];
    float t = 0.f;
    #pragma unroll
    for (int c = 0; c < 4; ++c) { e[c] = expf(s[c] - m); t += e[c]; }
    #pragma unroll
    for (int off = 32; off > 0; off >>= 1)
        t += __shfl_xor(t, off);
    if (lane == 0) reds[wid] = t;
    __syncthreads();
    t = reds[0] + reds[1] + reds[2] + reds[3];
    float inv = 1.0f / t;
    float4 o;
    o.x = e[0] * inv; o.y = e[1] * inv; o.z = e[2] * inv; o.w = e[3] * inv;
    *(float4*)&row[tid << 2] = o;
}

// ---------------------------------------------------------------------------
// ctx = attn @ V (unchanged, fp32 out).
// ---------------------------------------------------------------------------
__global__ __launch_bounds__(256) void ctx_kernel(
    const float* __restrict__ attn, const float* __restrict__ qkv,
    float* __restrict__ ctx)
{
    const int qt = blockIdx.x, bh = blockIdx.y;
    const int b = bh >> 4, h = bh & 15;
    const int q0 = qt << 6;
    const int tid = threadIdx.x, tx = tid & 15, ty = tid >> 4;
    __shared__ __align__(16) float At[64][68];
    __shared__ __align__(16) float Vs[64][68];
    float acc[4][4] = {};

    for (int k0 = 0; k0 <= q0; k0 += 64) {
        #pragma unroll
        for (int s = 0; s < 4; ++s) {
            int idx = s * 256 + tid;
            int r = idx >> 4, cc = (idx & 15) << 2;
            *(float4*)&At[r][cc] =
                *(const float4*)&attn[((((size_t)bh << 10) + q0 + r) << 10) + k0 + cc];
            *(float4*)&Vs[r][cc] =
                *(const float4*)&qkv[((size_t)(k0 + r) * 4 + b) * 3072 + h * 192 + 128 + cc];
        }
        __syncthreads();
        #pragma unroll
        for (int kk = 0; kk < 64; ++kk) {
            float a[4];
            #pragma unroll
            for (int i = 0; i < 4; ++i) a[i] = At[(ty << 2) + i][kk];
            float4 vv = *(const float4*)&Vs[kk][tx << 2];
            float vb[4] = {vv.x, vv.y, vv.z, vv.w};
            #pragma unroll
            for (int i = 0; i < 4; ++i)
            #pragma unroll
            for (int j = 0; j < 4; ++j)
                acc[i][j] += a[i] * vb[j];
        }
        __syncthreads();
    }

    #pragma unroll
    for (int i = 0; i < 4; ++i) {
        int q = q0 + (ty << 2) + i;
        float4 o;
        o.x = acc[i][0]; o.y = acc[i][1]; o.z = acc[i][2]; o.w = acc[i][3];
        *(float4*)&ctx[((size_t)q * 4 + b) * 1024 + (h << 6) + (tx << 2)] = o;
    }
}

// ---------------------------------------------------------------------------
extern "C" void kernel_launch(void* const* d_in, const int* in_sizes, int n_in,
                              void* d_out, int out_size, void* d_ws, size_t ws_size,
                              hipStream_t stream)
{
    (void)in_sizes; (void)n_in; (void)out_size; (void)ws_size;
    const float* x     = (const float*)d_in[0];
    const float* pos   = (const float*)d_in[1];
    const float* w_in  = (const float*)d_in[2];
    const float* b_in  = (const float*)d_in[3];
    const float* w_out = (const float*)d_in[4];
    const float* b_out = (const float*)d_in[5];
    const float* w_pos = (const float*)d_in[6];
    const float* b_pos = (const float*)d_in[7];
    const float* rwb   = (const float*)d_in[8];
    const float* rrb   = (const float*)d_in[9];
    // d_in[10] = attn_mask: causal triu(k=1) by construction — handled analytically.

    float* out  = (float*)d_out;                       // (T,B,E)    4,194,304
    float* attn = out + (size_t)TQ * BBATCH * EDIM;    // (B,H,T,T) 67,108,864

    float* ws  = (float*)d_ws;
    float* qkv = ws;                                   // 4096 x 3072
    float* R   = qkv + (size_t)4096 * 3072;            // [H][T][D]
    float* ctx = R + (size_t)HHEADS * TQ * DHEAD;      // (T,B,E)

    dim3 blk(256, 1, 1);

    // 1) qkv = x2d @ W_in^T + b_in        (4096 x 3072, bf16 MFMA, fp32 out)
    gemm_mfma_abt<0><<<dim3(3072 / 128, 4096 / 128), blk, 0, stream>>>(
        x, w_in, b_in, qkv, 4096, 3072, 1024);
    // 2) r_head_k = pos @ W_pos^T + b_pos -> R[h][t][d]
    gemm_mfma_abt<1><<<dim3(1024 / 128, 1024 / 128), blk, 0, stream>>>(
        pos, w_pos, b_pos, R, 1024, 1024, 1024);
    // 3) scores -> attn region (lower-triangle tiles only)
    score_kernel<<<dim3(16, 16, 64), blk, 0, stream>>>(qkv, R, rwb, rrb, attn);
    // 4) in-place causal softmax (writes zeros above diagonal)
    softmax_kernel<<<dim3(1024, 64), blk, 0, stream>>>(attn);
    // 5) ctx = attn @ V
    ctx_kernel<<<dim3(16, 64), blk, 0, stream>>>(attn, qkv, ctx);
    // 6) out = ctx2d @ W_out^T + b_out
    gemm_mfma_abt<0><<<dim3(1024 / 128, 4096 / 128), blk, 0, stream>>>(
        ctx, w_out, b_out, out, 4096, 1024, 1024);
}

// Round 3
// 434.403 us; speedup vs baseline: 2.6425x; 1.7223x over previous
//
#include <hip/hip_runtime.h>
#include <math.h>

// Problem constants (T=1024, B=4, E=1024, H=16, D=64)
#define TQ 1024
#define BBATCH 4
#define EDIM 1024
#define HHEADS 16
#define DHEAD 64

typedef __bf16 bf16x8 __attribute__((ext_vector_type(8)));
typedef __bf16 bf16x4 __attribute__((ext_vector_type(4)));
typedef float  f32x4  __attribute__((ext_vector_type(4)));

#define LDK 40  // GEMM LDS row stride (bf16): 32 + 8 pad

// ---------------------------------------------------------------------------
// MFMA GEMM: C = A * B^T + bias (fp32 in/out, bf16 MFMA internally).
// MODE 0: C[m][n] linear.  MODE 1: scatter to R[h][t][d].
// ---------------------------------------------------------------------------
template<int MODE>
__global__ __launch_bounds__(256) void gemm_mfma_abt(
    const float* __restrict__ A, const float* __restrict__ B,
    const float* __restrict__ bias, float* __restrict__ C,
    int M, int N, int K)
{
    __shared__ __bf16 As[128 * LDK];
    __shared__ __bf16 Bs[128 * LDK];
    const int tid  = threadIdx.x;
    const int lane = tid & 63;
    const int wid  = tid >> 6;
    const int wr   = wid >> 1, wc = wid & 1;
    const int m0 = blockIdx.y * 128, n0 = blockIdx.x * 128;

    f32x4 acc[4][4] = {};

    const int sm0 = tid >> 2;
    const int sm1 = sm0 + 64;
    const int sk  = (tid & 3) << 3;

    const int fr = lane & 15;
    const int kg = (lane >> 4) << 3;

    for (int k0 = 0; k0 < K; k0 += 32) {
        float4 ra0a = *(const float4*)&A[(size_t)(m0 + sm0) * K + k0 + sk];
        float4 ra0b = *(const float4*)&A[(size_t)(m0 + sm0) * K + k0 + sk + 4];
        float4 ra1a = *(const float4*)&A[(size_t)(m0 + sm1) * K + k0 + sk];
        float4 ra1b = *(const float4*)&A[(size_t)(m0 + sm1) * K + k0 + sk + 4];
        float4 rb0a = *(const float4*)&B[(size_t)(n0 + sm0) * K + k0 + sk];
        float4 rb0b = *(const float4*)&B[(size_t)(n0 + sm0) * K + k0 + sk + 4];
        float4 rb1a = *(const float4*)&B[(size_t)(n0 + sm1) * K + k0 + sk];
        float4 rb1b = *(const float4*)&B[(size_t)(n0 + sm1) * K + k0 + sk + 4];

        __syncthreads();

        bf16x8 w;
        w[0]=(__bf16)ra0a.x; w[1]=(__bf16)ra0a.y; w[2]=(__bf16)ra0a.z; w[3]=(__bf16)ra0a.w;
        w[4]=(__bf16)ra0b.x; w[5]=(__bf16)ra0b.y; w[6]=(__bf16)ra0b.z; w[7]=(__bf16)ra0b.w;
        *(bf16x8*)&As[sm0 * LDK + sk] = w;
        w[0]=(__bf16)ra1a.x; w[1]=(__bf16)ra1a.y; w[2]=(__bf16)ra1a.z; w[3]=(__bf16)ra1a.w;
        w[4]=(__bf16)ra1b.x; w[5]=(__bf16)ra1b.y; w[6]=(__bf16)ra1b.z; w[7]=(__bf16)ra1b.w;
        *(bf16x8*)&As[sm1 * LDK + sk] = w;
        w[0]=(__bf16)rb0a.x; w[1]=(__bf16)rb0a.y; w[2]=(__bf16)rb0a.z; w[3]=(__bf16)rb0a.w;
        w[4]=(__bf16)rb0b.x; w[5]=(__bf16)rb0b.y; w[6]=(__bf16)rb0b.z; w[7]=(__bf16)rb0b.w;
        *(bf16x8*)&Bs[sm0 * LDK + sk] = w;
        w[0]=(__bf16)rb1a.x; w[1]=(__bf16)rb1a.y; w[2]=(__bf16)rb1a.z; w[3]=(__bf16)rb1a.w;
        w[4]=(__bf16)rb1b.x; w[5]=(__bf16)rb1b.y; w[6]=(__bf16)rb1b.z; w[7]=(__bf16)rb1b.w;
        *(bf16x8*)&Bs[sm1 * LDK + sk] = w;

        __syncthreads();

        bf16x8 af[4], bfr[4];
        #pragma unroll
        for (int i = 0; i < 4; ++i) {
            af[i]  = *(const bf16x8*)&As[(wr * 64 + i * 16 + fr) * LDK + kg];
            bfr[i] = *(const bf16x8*)&Bs[(wc * 64 + i * 16 + fr) * LDK + kg];
        }
        #pragma unroll
        for (int mi = 0; mi < 4; ++mi)
        #pragma unroll
        for (int ni = 0; ni < 4; ++ni)
            acc[mi][ni] = __builtin_amdgcn_mfma_f32_16x16x32_bf16(
                af[mi], bfr[ni], acc[mi][ni], 0, 0, 0);
    }

    const int fq = lane >> 4;
    #pragma unroll
    for (int mi = 0; mi < 4; ++mi)
    #pragma unroll
    for (int ni = 0; ni < 4; ++ni) {
        int row = m0 + wr * 64 + mi * 16 + fq * 4;
        int col = n0 + wc * 64 + ni * 16 + fr;
        float bv = bias[col];
        #pragma unroll
        for (int j = 0; j < 4; ++j) {
            float v = acc[mi][ni][j] + bv;
            if (MODE == 0) {
                C[(size_t)(row + j) * N + col] = v;
            } else {
                C[(((size_t)(col >> 6) << 10) + (row + j)) * 64 + (col & 63)] = v;
            }
        }
    }
}

// ---------------------------------------------------------------------------
// bias_dots: cK[bh][k] = rwb[h] . K[k,b,h,:]   (fp32, exact split of (Q+rwb).K)
//            cR[h][j]  = rrb[h] . R[h][j][:]
// ---------------------------------------------------------------------------
__global__ __launch_bounds__(256) void bias_dots_kernel(
    const float* __restrict__ qkv, const float* __restrict__ Rm,
    const float* __restrict__ rwb, const float* __restrict__ rrb,
    float* __restrict__ cK, float* __restrict__ cR)
{
    int id = blockIdx.x * 256 + threadIdx.x;
    if (id < 65536) {
        int bh = id >> 10, k = id & 1023;
        int b = bh >> 4, h = bh & 15;
        const float* p = &qkv[((size_t)k * 4 + b) * 3072 + h * 192 + 64];
        const float* w = &rwb[h << 6];
        float s = 0.f;
        #pragma unroll
        for (int d = 0; d < 64; d += 4) {
            float4 v = *(const float4*)&p[d];
            s += v.x * w[d] + v.y * w[d + 1] + v.z * w[d + 2] + v.w * w[d + 3];
        }
        cK[id] = s;
    } else if (id < 81920) {
        int id2 = id - 65536;
        int h = id2 >> 10, j = id2 & 1023;
        const float* p = &Rm[(((size_t)h << 10) + j) * 64];
        const float* w = &rrb[h << 6];
        float s = 0.f;
        #pragma unroll
        for (int d = 0; d < 64; d += 4) {
            float4 v = *(const float4*)&p[d];
            s += v.x * w[d] + v.y * w[d + 1] + v.z * w[d + 2] + v.w * w[d + 3];
        }
        cR[id2] = s;
    }
}

// ---------------------------------------------------------------------------
// MFMA score kernel. One block = one (bh, lower-triangle 64x64 tile).
//  S[q][k] = 0.125*( Q.K + cK[k] + BDwin[q][k-q+63] + cR[base_j+k-q+63] )
// BD computed as Q.R_win^T via MFMA in two 64-col halves; fragments spilled
// to wave-local rows of an LDS scratch and gathered along the shifted diag.
// ---------------------------------------------------------------------------
#define SLD 72  // bf16 LDS row stride for 64-wide tiles

__global__ __launch_bounds__(256) void score_mfma_kernel(
    const float* __restrict__ qkv, const float* __restrict__ Rm,
    const float* __restrict__ cK, const float* __restrict__ cR,
    float* __restrict__ attn)
{
    // triangular tile decode: t -> (qt, kt), kt <= qt
    int t = blockIdx.x;
    int qt = (int)((sqrtf(8.f * t + 1.f) - 1.f) * 0.5f);
    while ((qt + 1) * (qt + 2) / 2 <= t) ++qt;
    while (qt * (qt + 1) / 2 > t) --qt;
    int kt = t - qt * (qt + 1) / 2;

    const int bh = blockIdx.y;
    const int b = bh >> 4, h = bh & 15;
    const int q0 = qt << 6, k0 = kt << 6;
    const int tid = threadIdx.x, lane = tid & 63, wid = tid >> 6;
    const int fr = lane & 15, fq = lane >> 4, kg = fq << 3;
    const int w16 = wid << 4;
    const int base_j = k0 - q0 + 960;

    __shared__ __bf16 Qs[64 * SLD];
    __shared__ __bf16 Ks[64 * SLD];
    __shared__ __bf16 Rs[64 * SLD];
    __shared__ float  BDs[64][68];

    // ---- stage: load Q,K,R0,R1 (fp32), write Q,K,R0 as bf16 ----
    float4 qreg[4], kreg[4], r0reg[4], r1reg[4];
    #pragma unroll
    for (int s = 0; s < 4; ++s) {
        int idx = (s << 8) + tid;
        int r = idx >> 4, dc = (idx & 15) << 2;
        qreg[s] = *(const float4*)&qkv[((size_t)(q0 + r) * 4 + b) * 3072 + h * 192 + dc];
        kreg[s] = *(const float4*)&qkv[((size_t)(k0 + r) * 4 + b) * 3072 + h * 192 + 64 + dc];
        int j0 = base_j + r;       if (j0 > 1023) j0 = 1023;
        int j1 = base_j + 64 + r;  if (j1 > 1023) j1 = 1023;
        r0reg[s] = *(const float4*)&Rm[(((size_t)h << 10) + j0) * 64 + dc];
        r1reg[s] = *(const float4*)&Rm[(((size_t)h << 10) + j1) * 64 + dc];
    }
    #pragma unroll
    for (int s = 0; s < 4; ++s) {
        int idx = (s << 8) + tid;
        int r = idx >> 4, dc = (idx & 15) << 2;
        bf16x4 w;
        w[0]=(__bf16)qreg[s].x; w[1]=(__bf16)qreg[s].y; w[2]=(__bf16)qreg[s].z; w[3]=(__bf16)qreg[s].w;
        *(bf16x4*)&Qs[r * SLD + dc] = w;
        w[0]=(__bf16)kreg[s].x; w[1]=(__bf16)kreg[s].y; w[2]=(__bf16)kreg[s].z; w[3]=(__bf16)kreg[s].w;
        *(bf16x4*)&Ks[r * SLD + dc] = w;
        w[0]=(__bf16)r0reg[s].x; w[1]=(__bf16)r0reg[s].y; w[2]=(__bf16)r0reg[s].z; w[3]=(__bf16)r0reg[s].w;
        *(bf16x4*)&Rs[r * SLD + dc] = w;
    }
    __syncthreads();

    // ---- A fragments (wave's 16 q-rows) ----
    bf16x8 af0 = *(const bf16x8*)&Qs[(w16 + fr) * SLD + kg];
    bf16x8 af1 = *(const bf16x8*)&Qs[(w16 + fr) * SLD + 32 + kg];

    f32x4 aac[4], abd[4];
    const f32x4 zero4 = {0.f, 0.f, 0.f, 0.f};

    // AC = Q.K^T
    #pragma unroll
    for (int ni = 0; ni < 4; ++ni) {
        bf16x8 b0 = *(const bf16x8*)&Ks[(ni * 16 + fr) * SLD + kg];
        bf16x8 b1 = *(const bf16x8*)&Ks[(ni * 16 + fr) * SLD + 32 + kg];
        aac[ni] = __builtin_amdgcn_mfma_f32_16x16x32_bf16(af0, b0, zero4, 0, 0, 0);
        aac[ni] = __builtin_amdgcn_mfma_f32_16x16x32_bf16(af1, b1, aac[ni], 0, 0, 0);
    }
    // BD half 0 (widx 0..63)
    #pragma unroll
    for (int ni = 0; ni < 4; ++ni) {
        bf16x8 b0 = *(const bf16x8*)&Rs[(ni * 16 + fr) * SLD + kg];
        bf16x8 b1 = *(const bf16x8*)&Rs[(ni * 16 + fr) * SLD + 32 + kg];
        abd[ni] = __builtin_amdgcn_mfma_f32_16x16x32_bf16(af0, b0, zero4, 0, 0, 0);
        abd[ni] = __builtin_amdgcn_mfma_f32_16x16x32_bf16(af1, b1, abd[ni], 0, 0, 0);
    }
    // spill BD frags to wave-local rows, gather shifted diag (half 0)
    #pragma unroll
    for (int ni = 0; ni < 4; ++ni)
    #pragma unroll
    for (int j = 0; j < 4; ++j)
        BDs[w16 + fq * 4 + j][ni * 16 + fr] = abd[ni][j];
    asm volatile("s_waitcnt lgkmcnt(0)" ::: "memory");
    #pragma unroll
    for (int ni = 0; ni < 4; ++ni)
    #pragma unroll
    for (int j = 0; j < 4; ++j) {
        int lrow = w16 + fq * 4 + j;
        int widx = (ni * 16 + fr) - lrow + 63;   // 0..126
        if (widx < 64) aac[ni][j] += BDs[lrow][widx];
    }
    __syncthreads();   // all waves done with Rs(half0) fragment reads

    // stage R half 1
    #pragma unroll
    for (int s = 0; s < 4; ++s) {
        int idx = (s << 8) + tid;
        int r = idx >> 4, dc = (idx & 15) << 2;
        bf16x4 w;
        w[0]=(__bf16)r1reg[s].x; w[1]=(__bf16)r1reg[s].y; w[2]=(__bf16)r1reg[s].z; w[3]=(__bf16)r1reg[s].w;
        *(bf16x4*)&Rs[r * SLD + dc] = w;
    }
    __syncthreads();   // Rs(half1) visible

    // BD half 1 (widx 64..127)
    #pragma unroll
    for (int ni = 0; ni < 4; ++ni) {
        bf16x8 b0 = *(const bf16x8*)&Rs[(ni * 16 + fr) * SLD + kg];
        bf16x8 b1 = *(const bf16x8*)&Rs[(ni * 16 + fr) * SLD + 32 + kg];
        abd[ni] = __builtin_amdgcn_mfma_f32_16x16x32_bf16(af0, b0, zero4, 0, 0, 0);
        abd[ni] = __builtin_amdgcn_mfma_f32_16x16x32_bf16(af1, b1, abd[ni], 0, 0, 0);
    }
    #pragma unroll
    for (int ni = 0; ni < 4; ++ni)
    #pragma unroll
    for (int j = 0; j < 4; ++j)
        BDs[w16 + fq * 4 + j][ni * 16 + fr] = abd[ni][j];
    asm volatile("s_waitcnt lgkmcnt(0)" ::: "memory");
    #pragma unroll
    for (int ni = 0; ni < 4; ++ni)
    #pragma unroll
    for (int j = 0; j < 4; ++j) {
        int lrow = w16 + fq * 4 + j;
        int widx = (ni * 16 + fr) - lrow + 63;
        if (widx >= 64) aac[ni][j] += BDs[lrow][widx - 64];
    }

    // ---- epilogue: + cK + cR, scale, store ----
    #pragma unroll
    for (int ni = 0; ni < 4; ++ni) {
        int lcol = ni * 16 + fr;
        int k = k0 + lcol;
        float ckv = cK[(bh << 10) + k];
        #pragma unroll
        for (int j = 0; j < 4; ++j) {
            int lrow = w16 + fq * 4 + j;
            int q = q0 + lrow;
            int widx = lcol - lrow + 63;
            int jidx = base_j + widx; if (jidx > 1023) jidx = 1023;
            float crv = cR[(h << 10) + jidx];
            float v = 0.125f * (aac[ni][j] + ckv + crv);
            attn[((((size_t)bh << 10) + q) << 10) + k] = v;
        }
    }
}

// ---------------------------------------------------------------------------
// In-place causal softmax (unchanged).
// ---------------------------------------------------------------------------
__global__ __launch_bounds__(256) void softmax_kernel(float* __restrict__ attn)
{
    const int q = blockIdx.x, bh = blockIdx.y;
    float* row = attn + ((((size_t)bh << 10) + q) << 10);
    const int tid = threadIdx.x;
    float4 v = *(const float4*)&row[tid << 2];
    float s[4] = {v.x, v.y, v.z, v.w};
    #pragma unroll
    for (int c = 0; c < 4; ++c)
        if (((tid << 2) + c) > q) s[c] = -INFINITY;

    float m = fmaxf(fmaxf(s[0], s[1]), fmaxf(s[2], s[3]));
    #pragma unroll
    for (int off = 32; off > 0; off >>= 1)
        m = fmaxf(m, __shfl_xor(m, off));
    __shared__ float redm[4];
    __shared__ float reds[4];
    const int lane = tid & 63, wid = tid >> 6;
    if (lane == 0) redm[wid] = m;
    __syncthreads();
    m = fmaxf(fmaxf(redm[0], redm[1]), fmaxf(redm[2], redm[3]));

    float e[4];
    float t = 0.f;
    #pragma unroll
    for (int c = 0; c < 4; ++c) { e[c] = expf(s[c] - m); t += e[c]; }
    #pragma unroll
    for (int off = 32; off > 0; off >>= 1)
        t += __shfl_xor(t, off);
    if (lane == 0) reds[wid] = t;
    __syncthreads();
    t = reds[0] + reds[1] + reds[2] + reds[3];
    float inv = 1.0f / t;
    float4 o;
    o.x = e[0] * inv; o.y = e[1] * inv; o.z = e[2] * inv; o.w = e[3] * inv;
    *(float4*)&row[tid << 2] = o;
}

// ---------------------------------------------------------------------------
// ctx = attn @ V (unchanged, fp32).
// ---------------------------------------------------------------------------
__global__ __launch_bounds__(256) void ctx_kernel(
    const float* __restrict__ attn, const float* __restrict__ qkv,
    float* __restrict__ ctx)
{
    const int qt = blockIdx.x, bh = blockIdx.y;
    const int b = bh >> 4, h = bh & 15;
    const int q0 = qt << 6;
    const int tid = threadIdx.x, tx = tid & 15, ty = tid >> 4;
    __shared__ __align__(16) float At[64][68];
    __shared__ __align__(16) float Vs[64][68];
    float acc[4][4] = {};

    for (int k0 = 0; k0 <= q0; k0 += 64) {
        #pragma unroll
        for (int s = 0; s < 4; ++s) {
            int idx = s * 256 + tid;
            int r = idx >> 4, cc = (idx & 15) << 2;
            *(float4*)&At[r][cc] =
                *(const float4*)&attn[((((size_t)bh << 10) + q0 + r) << 10) + k0 + cc];
            *(float4*)&Vs[r][cc] =
                *(const float4*)&qkv[((size_t)(k0 + r) * 4 + b) * 3072 + h * 192 + 128 + cc];
        }
        __syncthreads();
        #pragma unroll
        for (int kk = 0; kk < 64; ++kk) {
            float a[4];
            #pragma unroll
            for (int i = 0; i < 4; ++i) a[i] = At[(ty << 2) + i][kk];
            float4 vv = *(const float4*)&Vs[kk][tx << 2];
            float vb[4] = {vv.x, vv.y, vv.z, vv.w};
            #pragma unroll
            for (int i = 0; i < 4; ++i)
            #pragma unroll
            for (int j = 0; j < 4; ++j)
                acc[i][j] += a[i] * vb[j];
        }
        __syncthreads();
    }

    #pragma unroll
    for (int i = 0; i < 4; ++i) {
        int q = q0 + (ty << 2) + i;
        float4 o;
        o.x = acc[i][0]; o.y = acc[i][1]; o.z = acc[i][2]; o.w = acc[i][3];
        *(float4*)&ctx[((size_t)q * 4 + b) * 1024 + (h << 6) + (tx << 2)] = o;
    }
}

// ---------------------------------------------------------------------------
extern "C" void kernel_launch(void* const* d_in, const int* in_sizes, int n_in,
                              void* d_out, int out_size, void* d_ws, size_t ws_size,
                              hipStream_t stream)
{
    (void)in_sizes; (void)n_in; (void)out_size; (void)ws_size;
    const float* x     = (const float*)d_in[0];
    const float* pos   = (const float*)d_in[1];
    const float* w_in  = (const float*)d_in[2];
    const float* b_in  = (const float*)d_in[3];
    const float* w_out = (const float*)d_in[4];
    const float* b_out = (const float*)d_in[5];
    const float* w_pos = (const float*)d_in[6];
    const float* b_pos = (const float*)d_in[7];
    const float* rwb   = (const float*)d_in[8];
    const float* rrb   = (const float*)d_in[9];
    // d_in[10] = attn_mask: causal triu(k=1) by construction — handled analytically.

    float* out  = (float*)d_out;                       // (T,B,E)    4,194,304
    float* attn = out + (size_t)TQ * BBATCH * EDIM;    // (B,H,T,T) 67,108,864

    float* ws  = (float*)d_ws;
    float* qkv = ws;                                   // 4096 x 3072
    float* R   = qkv + (size_t)4096 * 3072;            // [H][T][D]
    float* ctx = R + (size_t)HHEADS * TQ * DHEAD;      // (T,B,E)
    // cK/cR live inside the ctx region (consumed by score before ctx is written)
    float* cK  = ctx;                                  // [64][1024]
    float* cR  = ctx + 65536;                          // [16][1024]

    dim3 blk(256, 1, 1);

    // 1) qkv = x2d @ W_in^T + b_in        (bf16 MFMA, fp32 out)
    gemm_mfma_abt<0><<<dim3(3072 / 128, 4096 / 128), blk, 0, stream>>>(
        x, w_in, b_in, qkv, 4096, 3072, 1024);
    // 2) r_head_k = pos @ W_pos^T + b_pos -> R[h][t][d]
    gemm_mfma_abt<1><<<dim3(1024 / 128, 1024 / 128), blk, 0, stream>>>(
        pos, w_pos, b_pos, R, 1024, 1024, 1024);
    // 3) bias-dot corrections (exact fp32 split of (Q+bias).K / (Q+bias).R)
    bias_dots_kernel<<<dim3(320), blk, 0, stream>>>(qkv, R, rwb, rrb, cK, cR);
    // 4) scores -> attn region (136 lower-triangle tiles per bh, MFMA)
    score_mfma_kernel<<<dim3(136, 64), blk, 0, stream>>>(qkv, R, cK, cR, attn);
    // 5) in-place causal softmax (writes zeros above diagonal)
    softmax_kernel<<<dim3(1024, 64), blk, 0, stream>>>(attn);
    // 6) ctx = attn @ V
    ctx_kernel<<<dim3(16, 64), blk, 0, stream>>>(attn, qkv, ctx);
    // 7) out = ctx2d @ W_out^T + b_out
    gemm_mfma_abt<0><<<dim3(1024 / 128, 4096 / 128), blk, 0, stream>>>(
        ctx, w_out, b_out, out, 4096, 1024, 1024);
}